// Round 5
// baseline (290.477 us; speedup 1.0000x reference)
//
#include <hip/hip_runtime.h>
#include <hip/hip_fp16.h>
#include <cstdint>
#include <cstddef>

#define GLOBAL_AS __attribute__((address_space(1)))
#define LDS_AS    __attribute__((address_space(3)))

typedef __attribute__((ext_vector_type(8))) _Float16 f16x8;
typedef __attribute__((ext_vector_type(4))) float    f32x4;

__device__ __forceinline__ void gload_lds16(const void* g, void* l) {
    __builtin_amdgcn_global_load_lds((const GLOBAL_AS void*)g,
                                     (LDS_AS void*)l, 16, 0, 0);
}

// fp16 quantizer == reference fp_quantize_ste(exp=5, sig=10): RNE + saturate.
__device__ __forceinline__ __half qcvt(float x) {
    x = fminf(fmaxf(x, -65504.f), 65504.f);
    return __float2half(x);   // v_cvt_f16_f32: RNE, subnormals handled
}

// Fused quantization of x and w (both f32 -> f16), one launch, grid-stride.
__global__ void quant_xw_f32_to_f16(const float* __restrict__ xin, int x4,
                                    const float* __restrict__ win, int w4,
                                    __half* __restrict__ xout,
                                    __half* __restrict__ wout) {
    const int stride = gridDim.x * blockDim.x;
    const int tot = x4 + w4;
    for (int i = blockIdx.x * blockDim.x + threadIdx.x; i < tot; i += stride) {
        const bool isx = (i < x4);
        const int  j   = isx ? i : i - x4;
        const float4 f = reinterpret_cast<const float4*>(isx ? xin : win)[j];
        union { __half h[4]; uint2 u; } p;
        p.h[0] = qcvt(f.x);
        p.h[1] = qcvt(f.y);
        p.h[2] = qcvt(f.z);
        p.h[3] = qcvt(f.w);
        reinterpret_cast<uint2*>(isx ? xout : wout)[j] = p.u;
    }
}

// ---------------------------------------------------------------------------
// 256x256 tile, BK=64, 8 waves (2Mx4N), 8-phase schedule — m201 template
// barrier idiom EXACTLY: bare s_barrier builtins (no asm-memory wrappers),
// waitcnt asms WITHOUT memory clobbers (so SIInsertWaitcnts doesn't force a
// full counter drain at each phase), sched_barrier(0) after lgkmcnt(0) to pin
// MFMA below the wait (rule #18). B0 fragments stay in registers (P3 pure MFMA).
//
// Phases: P0=(A0,B0) P1=(A0,B1) P2=(A1,B1) P3=(A1,B0)
// Reads/wave: P0: bf0(4)+af(8)  P1: bf1(4)  P2: af<-A1(8)  P3: none
// Staging:    P0: B0(t+1)->nxt  P1: A0(t+2)->cur  P2: B1(t+2)->cur
//             P3: A1(t+2)->cur, then vmcnt(6) (tile t+1 fully retired).
// ---------------------------------------------------------------------------
__global__ __launch_bounds__(512, 2) void gemm_f16_8phase(
    const __half* __restrict__ A, const __half* __restrict__ B,
    const float* __restrict__ bias, float* __restrict__ C,
    int M, int N, int K)
{
    __shared__ __align__(16) __half lds[2][2][2][8192];   // 128 KiB

    const int tid  = threadIdx.x;
    const int lane = tid & 63;
    const int wid  = tid >> 6;     // 8 waves
    const int wr   = wid >> 2;     // 0..1 (M)
    const int wc   = wid & 3;      // 0..3 (N)
    const int fr   = lane & 15;
    const int fq   = lane >> 4;

    // bijective XCD swizzle (m204)
    const int nwg = gridDim.x;
    const int qq = nwg >> 3, rr = nwg & 7;
    const int xcd = blockIdx.x & 7, idx = blockIdx.x >> 3;
    const int wgid = (xcd < rr ? xcd * (qq + 1)
                               : rr * (qq + 1) + (xcd - rr) * qq) + idx;
    const int nbn = N >> 8;
    const int tile_m = (wgid / nbn) << 8;
    const int tile_n = (wgid % nbn) << 8;

    // ---- staging source coords (inverse of LDS swizzle, per thread) ----
    const int wbyte = (lane * 16) ^ (((lane >> 5) & 1) << 5);
    const int srow  = ((wid >> 1) << 4) + (wbyte >> 6);   // 0..63
    const int scb   = ((wid & 1) << 6) + (wbyte & 63);    // col byte 0..127
    const char* gA0 = (const char*)A + (size_t)(tile_m + srow) * K * 2 + scb;
    const char* gB0 = (const char*)B + (size_t)(tile_n + srow) * K * 2 + scb;
    const size_t rstep = (size_t)64  * K * 2;   // +64 rows
    const size_t hstep = (size_t)128 * K * 2;   // +1 half (128 rows)
    const int ldst = tid * 16;                  // linear LDS dest byte

    // ---- fragment-read byte offsets (st_16x32 swizzled) ----
    const int woff  = (fr * 64 + fq * 16) ^ (((fr >> 3) & 1) << 5);
    const int aoff  = wr * 8192 + woff;     // + m*2048 + kk*1024
    const int boff  = wc * 4096 + woff;     // + n*2048 + kk*1024

    f32x4 acc[2][2][4][2];
#pragma unroll
    for (int qa = 0; qa < 2; ++qa)
#pragma unroll
        for (int qb = 0; qb < 2; ++qb)
#pragma unroll
            for (int m = 0; m < 4; ++m)
#pragma unroll
                for (int n = 0; n < 2; ++n)
                    acc[qa][qb][m][n] = (f32x4){0.f, 0.f, 0.f, 0.f};

    f16x8 af[4][2];        // A fragments (half 0, then reloaded for half 1)
    f16x8 bf0[2][2];       // B0 fragments (live whole tile: P0 and P3)
    f16x8 bf1[2][2];       // B1 fragments (P1, P2)

#define STAGE_A(bufi, h, kt) do {                                          \
        char* l_ = (char*)(&lds[bufi][0][h][0]) + ldst;                    \
        const char* g_ = gA0 + (size_t)(kt) * 128 + ((h) ? hstep : 0);     \
        gload_lds16(g_, l_);                                               \
        gload_lds16(g_ + rstep, l_ + 8192);                                \
    } while (0)

#define STAGE_B(bufi, h, kt) do {                                          \
        char* l_ = (char*)(&lds[bufi][1][h][0]) + ldst;                    \
        const char* g_ = gB0 + (size_t)(kt) * 128 + ((h) ? hstep : 0);     \
        gload_lds16(g_, l_);                                               \
        gload_lds16(g_ + rstep, l_ + 8192);                                \
    } while (0)

#define LDGA(bufi, qa) do {                                                \
        const char* lb_ = (const char*)(&lds[bufi][0][qa][0]) + aoff;      \
        _Pragma("unroll")                                                  \
        for (int m_ = 0; m_ < 4; ++m_) {                                   \
            af[m_][0] = *(const f16x8*)(lb_ + m_ * 2048);                  \
            af[m_][1] = *(const f16x8*)(lb_ + m_ * 2048 + 1024);           \
        }                                                                  \
    } while (0)

#define LDGB(dst, bufi, hb) do {                                           \
        const char* lb_ = (const char*)(&lds[bufi][1][hb][0]) + boff;      \
        _Pragma("unroll")                                                  \
        for (int n_ = 0; n_ < 2; ++n_) {                                   \
            dst[n_][0] = *(const f16x8*)(lb_ + n_ * 2048);                 \
            dst[n_][1] = *(const f16x8*)(lb_ + n_ * 2048 + 1024);          \
        }                                                                  \
    } while (0)

#define MMA(qa, qb, BF)                                                    \
    __builtin_amdgcn_s_setprio(1);                                         \
    _Pragma("unroll")                                                      \
    for (int m_ = 0; m_ < 4; ++m_) {                                       \
        _Pragma("unroll")                                                  \
        for (int n_ = 0; n_ < 2; ++n_) {                                   \
            acc[qa][qb][m_][n_] = __builtin_amdgcn_mfma_f32_16x16x32_f16(  \
                af[m_][0], BF[n_][0], acc[qa][qb][m_][n_], 0, 0, 0);       \
            acc[qa][qb][m_][n_] = __builtin_amdgcn_mfma_f32_16x16x32_f16(  \
                AF1_##qa(m_), BF[n_][1], acc[qa][qb][m_][n_], 0, 0, 0);    \
        }                                                                  \
    }                                                                      \
    __builtin_amdgcn_s_setprio(0);

// second-k-step A fragment (same array; macro indirection only for clarity)
#define AF1_0(m_) af[m_][1]
#define AF1_1(m_) af[m_][1]

// m201 template idiom: bare barrier, un-clobbered waitcnt, sched fence.
#define PH_WAIT_MMA()                                                      \
    __builtin_amdgcn_s_barrier();                                          \
    asm volatile("s_waitcnt lgkmcnt(0)");                                  \
    __builtin_amdgcn_sched_barrier(0)

#define PH_END()                                                           \
    __builtin_amdgcn_s_barrier()

#define TILE_FULL(cur, nxt, kt)                                            \
    LDGB(bf0, cur, 0); LDGA(cur, 0); STAGE_B(nxt, 0, (kt) + 1);            \
    asm volatile("s_waitcnt lgkmcnt(8)");                                  \
    PH_WAIT_MMA(); MMA(0, 0, bf0); PH_END();                               \
    LDGB(bf1, cur, 1); STAGE_A(cur, 0, (kt) + 2);                          \
    PH_WAIT_MMA(); MMA(0, 1, bf1); PH_END();                               \
    LDGA(cur, 1); STAGE_B(cur, 1, (kt) + 2);                               \
    PH_WAIT_MMA(); MMA(1, 1, bf1); PH_END();                               \
    STAGE_A(cur, 1, (kt) + 2);                                             \
    asm volatile("s_waitcnt vmcnt(6)");                                    \
    PH_WAIT_MMA(); MMA(1, 0, bf0); PH_END();

    // ---- prologue: stage tile0 fully + tile1 (A0,B1,A1); B0(1) in-loop ----
    STAGE_A(0, 0, 0); STAGE_B(0, 0, 0); STAGE_B(0, 1, 0); STAGE_A(0, 1, 0);
    STAGE_A(1, 0, 1); STAGE_B(1, 1, 1); STAGE_A(1, 1, 1);
    asm volatile("s_waitcnt vmcnt(6)");   // tile0 arrived
    __builtin_amdgcn_s_barrier();

    const int nt = K >> 6;              // even, >= 4 (guarded by launcher)
    for (int kt = 0; kt + 3 < nt; kt += 2) {
        TILE_FULL(0, 1, kt);
        TILE_FULL(1, 0, kt + 1);
    }

    // ---- tile nt-2 (buf0): stage only B0(nt-1); full drain at P3 ----
    LDGB(bf0, 0, 0); LDGA(0, 0); STAGE_B(1, 0, nt - 1);
    PH_WAIT_MMA(); MMA(0, 0, bf0); PH_END();
    LDGB(bf1, 0, 1);
    PH_WAIT_MMA(); MMA(0, 1, bf1); PH_END();
    LDGA(0, 1);
    PH_WAIT_MMA(); MMA(1, 1, bf1); PH_END();
    asm volatile("s_waitcnt vmcnt(0)");
    PH_WAIT_MMA(); MMA(1, 0, bf0); PH_END();

    // ---- tile nt-1 (buf1): pure compute ----
    LDGB(bf0, 1, 0); LDGA(1, 0);
    PH_WAIT_MMA(); MMA(0, 0, bf0); PH_END();
    LDGB(bf1, 1, 1);
    PH_WAIT_MMA(); MMA(0, 1, bf1); PH_END();
    LDGA(1, 1);
    PH_WAIT_MMA(); MMA(1, 1, bf1); PH_END();
    asm volatile("s_waitcnt lgkmcnt(0)");
    __builtin_amdgcn_sched_barrier(0);
    MMA(1, 0, bf0);

    // ---- epilogue: C/D layout col=lane&15, row=fq*4+reg (m89-verified) ----
    // bias quantized here (fp16 RNE) instead of a separate kernel.
    float bv[2][2];
#pragma unroll
    for (int qb = 0; qb < 2; ++qb)
#pragma unroll
        for (int n = 0; n < 2; ++n)
            bv[qb][n] = __half2float(qcvt(
                bias[tile_n + qb * 128 + wc * 32 + n * 16 + fr]));

#pragma unroll
    for (int qa = 0; qa < 2; ++qa)
#pragma unroll
        for (int qb = 0; qb < 2; ++qb)
#pragma unroll
            for (int m = 0; m < 4; ++m)
#pragma unroll
                for (int n = 0; n < 2; ++n) {
                    const int col = tile_n + qb * 128 + wc * 32 + n * 16 + fr;
                    const int rowb = tile_m + qa * 128 + wr * 64 + m * 16 + fq * 4;
#pragma unroll
                    for (int r = 0; r < 4; ++r)
                        C[(size_t)(rowb + r) * N + col] =
                            acc[qa][qb][m][n][r] + bv[qb][n];
                }

#undef STAGE_A
#undef STAGE_B
#undef LDGA
#undef LDGB
#undef MMA
#undef PH_WAIT_MMA
#undef PH_END
#undef TILE_FULL
}

// ---------------------------------------------------------------------------
// Insurance fallback (shape or ws mismatch): fused naive, slow but correct.
// ---------------------------------------------------------------------------
__global__ void qat_gemm_naive(const float* __restrict__ A,
                               const float* __restrict__ B,
                               const float* __restrict__ bias,
                               float* __restrict__ C, int M, int N, int K) {
    const int col = blockIdx.x * blockDim.x + threadIdx.x;
    const int row = blockIdx.y;
    if (col >= N || row >= M) return;
    float s = 0.f;
    for (int k = 0; k < K; ++k) {
        float a = __half2float(qcvt(A[(size_t)row * K + k]));
        float b = __half2float(qcvt(B[(size_t)col * K + k]));
        s += a * b;
    }
    C[(size_t)row * N + col] = s + __half2float(qcvt(bias[col]));
}

// ---------------------------------------------------------------------------
extern "C" void kernel_launch(void* const* d_in, const int* in_sizes, int n_in,
                              void* d_out, int out_size, void* d_ws,
                              size_t ws_size, hipStream_t stream) {
    const float* x = (const float*)d_in[0];
    const float* w = (const float*)d_in[1];
    const float* b = (const float*)d_in[2];
    float* out = (float*)d_out;

    const int xn = in_sizes[0];     // M*K
    const int wn = in_sizes[1];     // N*K
    const int N  = in_sizes[2];     // 4096
    const int K  = wn / N;          // 4096
    const int M  = xn / K;          // 8192

    const size_t need = (size_t)(xn + wn) * sizeof(__half);
    const bool ok = (M % 256 == 0) && (N % 256 == 0) &&
                    (K % 128 == 0) && (K >= 256);

    if (ws_size >= need && ok) {
        __half* xq = (__half*)d_ws;
        __half* wq = xq + xn;

        const int x4 = xn / 4, w4 = wn / 4;
        int blk = ((x4 + w4) + 255) / 256; if (blk > 2048) blk = 2048;
        quant_xw_f32_to_f16<<<blk, 256, 0, stream>>>(x, x4, w, w4, xq, wq);

        dim3 grid((M / 256) * (N / 256));
        gemm_f16_8phase<<<grid, 512, 0, stream>>>(xq, wq, b, out, M, N, K);
    } else {
        dim3 grid((N + 255) / 256, M);
        qat_gemm_naive<<<grid, 256, 0, stream>>>(x, w, b, out, M, N, K);
    }
}

// Round 6
// 288.248 us; speedup vs baseline: 1.0077x; 1.0077x over previous
//
#include <hip/hip_runtime.h>
#include <hip/hip_fp16.h>
#include <cstdint>
#include <cstddef>

#define GLOBAL_AS __attribute__((address_space(1)))
#define LDS_AS    __attribute__((address_space(3)))

typedef __attribute__((ext_vector_type(8))) _Float16 f16x8;
typedef __attribute__((ext_vector_type(4))) float    f32x4;

__device__ __forceinline__ void gload_lds16(const void* g, void* l) {
    __builtin_amdgcn_global_load_lds((const GLOBAL_AS void*)g,
                                     (LDS_AS void*)l, 16, 0, 0);
}

// fp16 quantizer == reference fp_quantize_ste(exp=5, sig=10): RNE + saturate.
__device__ __forceinline__ __half qcvt(float x) {
    x = fminf(fmaxf(x, -65504.f), 65504.f);
    return __float2half(x);   // v_cvt_f16_f32: RNE, subnormals handled
}

// Fused quantization of x and w (both f32 -> f16), one launch, grid-stride.
__global__ void quant_xw_f32_to_f16(const float* __restrict__ xin, int x4,
                                    const float* __restrict__ win, int w4,
                                    __half* __restrict__ xout,
                                    __half* __restrict__ wout) {
    const int stride = gridDim.x * blockDim.x;
    const int tot = x4 + w4;
    for (int i = blockIdx.x * blockDim.x + threadIdx.x; i < tot; i += stride) {
        const bool isx = (i < x4);
        const int  j   = isx ? i : i - x4;
        const float4 f = reinterpret_cast<const float4*>(isx ? xin : win)[j];
        union { __half h[4]; uint2 u; } p;
        p.h[0] = qcvt(f.x);
        p.h[1] = qcvt(f.y);
        p.h[2] = qcvt(f.z);
        p.h[3] = qcvt(f.w);
        reinterpret_cast<uint2*>(isx ? xout : wout)[j] = p.u;
    }
}

// ---------------------------------------------------------------------------
// 256x256 tile, BK=64, 8 waves (2Mx4N), 8-phase schedule (m201 template).
// ROUND 6 change: fragment reads are inline-asm ds_read_b128 (base VGPR +
// literal offset:), invisible to the compiler's LDS alias model, so
// SIInsertWaitcnts cannot insert conservative per-phase drains against the
// global_load_lds DMA queue. Synchronization is exclusively our own:
// per-phase s_waitcnt lgkmcnt(0) + sched_barrier(0) (rule #18), vmcnt(6)
// once per tile, raw s_barrier pairs. B0 fragments stay in registers
// across the tile (P3 pure MFMA).
//
// Phases: P0=(A0,B0) P1=(A0,B1) P2=(A1,B1) P3=(A1,B0)
// Reads/wave: P0: bf0(4)+af(8)  P1: bf1(4)  P2: af<-A1(8)  P3: none
// Staging:    P0: B0(t+1)->nxt  P1: A0(t+2)->cur  P2: B1(t+2)->cur
//             P3: A1(t+2)->cur, then vmcnt(6) (tile t+1 fully retired).
// ---------------------------------------------------------------------------
__global__ __launch_bounds__(512, 2) void gemm_f16_8phase(
    const __half* __restrict__ A, const __half* __restrict__ B,
    const float* __restrict__ bias, float* __restrict__ C,
    int M, int N, int K)
{
    __shared__ __align__(16) __half lds[2][2][2][8192];   // 128 KiB
    // layout: [buf](64KiB) [op A=0/B=1](32KiB) [half](16KiB) data

    const int tid  = threadIdx.x;
    const int lane = tid & 63;
    const int wid  = tid >> 6;     // 8 waves
    const int wr   = wid >> 2;     // 0..1 (M)
    const int wc   = wid & 3;      // 0..3 (N)
    const int fr   = lane & 15;
    const int fq   = lane >> 4;

    // bijective XCD swizzle (m204)
    const int nwg = gridDim.x;
    const int qq = nwg >> 3, rr = nwg & 7;
    const int xcd = blockIdx.x & 7, idx = blockIdx.x >> 3;
    const int wgid = (xcd < rr ? xcd * (qq + 1)
                               : rr * (qq + 1) + (xcd - rr) * qq) + idx;
    const int nbn = N >> 8;
    const int tile_m = (wgid / nbn) << 8;
    const int tile_n = (wgid % nbn) << 8;

    // ---- staging source coords (inverse of LDS swizzle, per thread) ----
    const int wbyte = (lane * 16) ^ (((lane >> 5) & 1) << 5);
    const int srow  = ((wid >> 1) << 4) + (wbyte >> 6);   // 0..63
    const int scb   = ((wid & 1) << 6) + (wbyte & 63);    // col byte 0..127
    const char* gA0 = (const char*)A + (size_t)(tile_m + srow) * K * 2 + scb;
    const char* gB0 = (const char*)B + (size_t)(tile_n + srow) * K * 2 + scb;
    const size_t rstep = (size_t)64  * K * 2;   // +64 rows
    const size_t hstep = (size_t)128 * K * 2;   // +1 half (128 rows)
    const int ldst = tid * 16;                  // linear LDS dest byte

    // ---- fragment-read LDS byte addresses (st_16x32 swizzled) ----
    const int woff = (fr * 64 + fq * 16) ^ (((fr >> 3) & 1) << 5);
    const uint32_t lds0 = (uint32_t)(size_t)(LDS_AS const char*)&lds[0][0][0][0];
    const uint32_t aBase = lds0 + (uint32_t)(wr * 8192 + woff);
    const uint32_t bBase = lds0 + 32768u + (uint32_t)(wc * 4096 + woff);

    f32x4 acc[2][2][4][2];
#pragma unroll
    for (int qa = 0; qa < 2; ++qa)
#pragma unroll
        for (int qb = 0; qb < 2; ++qb)
#pragma unroll
            for (int m = 0; m < 4; ++m)
#pragma unroll
                for (int n = 0; n < 2; ++n)
                    acc[qa][qb][m][n] = (f32x4){0.f, 0.f, 0.f, 0.f};

    f16x8 af[4][2];        // A fragments (half 0, then reloaded for half 1)
    f16x8 bf0[2][2];       // B0 fragments (live whole tile: P0 and P3)
    f16x8 bf1[2][2];       // B1 fragments (P1, P2)

#define STAGE_A(bufi, h, kt) do {                                          \
        char* l_ = (char*)(&lds[bufi][0][h][0]) + ldst;                    \
        const char* g_ = gA0 + (size_t)(kt) * 128 + ((h) ? hstep : 0);     \
        gload_lds16(g_, l_);                                               \
        gload_lds16(g_ + rstep, l_ + 8192);                                \
    } while (0)

#define STAGE_B(bufi, h, kt) do {                                          \
        char* l_ = (char*)(&lds[bufi][1][h][0]) + ldst;                    \
        const char* g_ = gB0 + (size_t)(kt) * 128 + ((h) ? hstep : 0);     \
        gload_lds16(g_, l_);                                               \
        gload_lds16(g_ + rstep, l_ + 8192);                                \
    } while (0)

// inline-asm ds_read_b128: base VGPR + literal offset (compiler cannot see
// the LDS access -> no conservative waitcnt insertion; we own all syncs)
#define DSR(dst, addr, OFF)                                                \
    asm volatile("ds_read_b128 %0, %1 offset:" OFF                         \
                 : "=v"(dst) : "v"(addr))

#define LDGA(bufi, qa) do {                                                \
        const uint32_t a_ = aBase + (bufi) * 65536u + (qa) * 16384u;       \
        DSR(af[0][0], a_, "0");    DSR(af[0][1], a_, "1024");              \
        DSR(af[1][0], a_, "2048"); DSR(af[1][1], a_, "3072");              \
        DSR(af[2][0], a_, "4096"); DSR(af[2][1], a_, "5120");              \
        DSR(af[3][0], a_, "6144"); DSR(af[3][1], a_, "7168");              \
    } while (0)

#define LDGB(dst, bufi, hb) do {                                           \
        const uint32_t b_ = bBase + (bufi) * 65536u + (hb) * 16384u;       \
        DSR(dst[0][0], b_, "0");    DSR(dst[0][1], b_, "1024");            \
        DSR(dst[1][0], b_, "2048"); DSR(dst[1][1], b_, "3072");            \
    } while (0)

#define MMA(qa, qb, BF)                                                    \
    __builtin_amdgcn_s_setprio(1);                                         \
    _Pragma("unroll")                                                      \
    for (int m_ = 0; m_ < 4; ++m_) {                                       \
        _Pragma("unroll")                                                  \
        for (int n_ = 0; n_ < 2; ++n_) {                                   \
            acc[qa][qb][m_][n_] = __builtin_amdgcn_mfma_f32_16x16x32_f16(  \
                af[m_][0], BF[n_][0], acc[qa][qb][m_][n_], 0, 0, 0);       \
            acc[qa][qb][m_][n_] = __builtin_amdgcn_mfma_f32_16x16x32_f16(  \
                af[m_][1], BF[n_][1], acc[qa][qb][m_][n_], 0, 0, 0);       \
        }                                                                  \
    }                                                                      \
    __builtin_amdgcn_s_setprio(0);

// bare barrier, un-clobbered waitcnt, sched fence (rule #18)
#define PH_WAIT_MMA()                                                      \
    __builtin_amdgcn_s_barrier();                                          \
    asm volatile("s_waitcnt lgkmcnt(0)");                                  \
    __builtin_amdgcn_sched_barrier(0)

#define PH_END()                                                           \
    __builtin_amdgcn_s_barrier()

#define TILE_FULL(cur, nxt, kt)                                            \
    LDGB(bf0, cur, 0); LDGA(cur, 0); STAGE_B(nxt, 0, (kt) + 1);            \
    asm volatile("s_waitcnt lgkmcnt(8)");                                  \
    PH_WAIT_MMA(); MMA(0, 0, bf0); PH_END();                               \
    LDGB(bf1, cur, 1); STAGE_A(cur, 0, (kt) + 2);                          \
    PH_WAIT_MMA(); MMA(0, 1, bf1); PH_END();                               \
    LDGA(cur, 1); STAGE_B(cur, 1, (kt) + 2);                               \
    PH_WAIT_MMA(); MMA(1, 1, bf1); PH_END();                               \
    STAGE_A(cur, 1, (kt) + 2);                                             \
    asm volatile("s_waitcnt vmcnt(6)");                                    \
    PH_WAIT_MMA(); MMA(1, 0, bf0); PH_END();

    // ---- prologue: stage tile0 fully + tile1 (A0,B1,A1); B0(1) in-loop ----
    STAGE_A(0, 0, 0); STAGE_B(0, 0, 0); STAGE_B(0, 1, 0); STAGE_A(0, 1, 0);
    STAGE_A(1, 0, 1); STAGE_B(1, 1, 1); STAGE_A(1, 1, 1);
    asm volatile("s_waitcnt vmcnt(6)");   // tile0 arrived
    __builtin_amdgcn_s_barrier();

    const int nt = K >> 6;              // even, >= 4 (guarded by launcher)
    for (int kt = 0; kt + 3 < nt; kt += 2) {
        TILE_FULL(0, 1, kt);
        TILE_FULL(1, 0, kt + 1);
    }

    // ---- tile nt-2 (buf0): stage only B0(nt-1); full drain at P3 ----
    LDGB(bf0, 0, 0); LDGA(0, 0); STAGE_B(1, 0, nt - 1);
    PH_WAIT_MMA(); MMA(0, 0, bf0); PH_END();
    LDGB(bf1, 0, 1);
    PH_WAIT_MMA(); MMA(0, 1, bf1); PH_END();
    LDGA(0, 1);
    PH_WAIT_MMA(); MMA(1, 1, bf1); PH_END();
    asm volatile("s_waitcnt vmcnt(0)");
    PH_WAIT_MMA(); MMA(1, 0, bf0); PH_END();

    // ---- tile nt-1 (buf1): pure compute ----
    LDGB(bf0, 1, 0); LDGA(1, 0);
    PH_WAIT_MMA(); MMA(0, 0, bf0); PH_END();
    LDGB(bf1, 1, 1);
    PH_WAIT_MMA(); MMA(0, 1, bf1); PH_END();
    LDGA(1, 1);
    PH_WAIT_MMA(); MMA(1, 1, bf1); PH_END();
    asm volatile("s_waitcnt lgkmcnt(0)");
    __builtin_amdgcn_sched_barrier(0);
    MMA(1, 0, bf0);

    // ---- epilogue: C/D layout col=lane&15, row=fq*4+reg (m89-verified) ----
    // bias quantized here (fp16 RNE) instead of a separate kernel.
    float bv[2][2];
#pragma unroll
    for (int qb = 0; qb < 2; ++qb)
#pragma unroll
        for (int n = 0; n < 2; ++n)
            bv[qb][n] = __half2float(qcvt(
                bias[tile_n + qb * 128 + wc * 32 + n * 16 + fr]));

#pragma unroll
    for (int qa = 0; qa < 2; ++qa)
#pragma unroll
        for (int qb = 0; qb < 2; ++qb)
#pragma unroll
            for (int m = 0; m < 4; ++m)
#pragma unroll
                for (int n = 0; n < 2; ++n) {
                    const int col = tile_n + qb * 128 + wc * 32 + n * 16 + fr;
                    const int rowb = tile_m + qa * 128 + wr * 64 + m * 16 + fq * 4;
#pragma unroll
                    for (int r = 0; r < 4; ++r)
                        C[(size_t)(rowb + r) * N + col] =
                            acc[qa][qb][m][n][r] + bv[qb][n];
                }

#undef STAGE_A
#undef STAGE_B
#undef DSR
#undef LDGA
#undef LDGB
#undef MMA
#undef PH_WAIT_MMA
#undef PH_END
#undef TILE_FULL
}

// ---------------------------------------------------------------------------
// Insurance fallback (shape or ws mismatch): fused naive, slow but correct.
// ---------------------------------------------------------------------------
__global__ void qat_gemm_naive(const float* __restrict__ A,
                               const float* __restrict__ B,
                               const float* __restrict__ bias,
                               float* __restrict__ C, int M, int N, int K) {
    const int col = blockIdx.x * blockDim.x + threadIdx.x;
    const int row = blockIdx.y;
    if (col >= N || row >= M) return;
    float s = 0.f;
    for (int k = 0; k < K; ++k) {
        float a = __half2float(qcvt(A[(size_t)row * K + k]));
        float b = __half2float(qcvt(B[(size_t)col * K + k]));
        s += a * b;
    }
    C[(size_t)row * N + col] = s + __half2float(qcvt(bias[col]));
}

// ---------------------------------------------------------------------------
extern "C" void kernel_launch(void* const* d_in, const int* in_sizes, int n_in,
                              void* d_out, int out_size, void* d_ws,
                              size_t ws_size, hipStream_t stream) {
    const float* x = (const float*)d_in[0];
    const float* w = (const float*)d_in[1];
    const float* b = (const float*)d_in[2];
    float* out = (float*)d_out;

    const int xn = in_sizes[0];     // M*K
    const int wn = in_sizes[1];     // N*K
    const int N  = in_sizes[2];     // 4096
    const int K  = wn / N;          // 4096
    const int M  = xn / K;          // 8192

    const size_t need = (size_t)(xn + wn) * sizeof(__half);
    const bool ok = (M % 256 == 0) && (N % 256 == 0) &&
                    (K % 128 == 0) && (K >= 256);

    if (ws_size >= need && ok) {
        __half* xq = (__half*)d_ws;
        __half* wq = xq + xn;

        const int x4 = xn / 4, w4 = wn / 4;
        int blk = ((x4 + w4) + 255) / 256; if (blk > 2048) blk = 2048;
        quant_xw_f32_to_f16<<<blk, 256, 0, stream>>>(x, x4, w, w4, xq, wq);

        dim3 grid((M / 256) * (N / 256));
        gemm_f16_8phase<<<grid, 512, 0, stream>>>(xq, wq, b, out, M, N, K);
    } else {
        dim3 grid((N + 255) / 256, M);
        qat_gemm_naive<<<grid, 256, 0, stream>>>(x, w, b, out, M, N, K);
    }
}

// Round 7
// 276.066 us; speedup vs baseline: 1.0522x; 1.0441x over previous
//
#include <hip/hip_runtime.h>
#include <hip/hip_fp16.h>
#include <cstdint>
#include <cstddef>

#define GLOBAL_AS __attribute__((address_space(1)))
#define LDS_AS    __attribute__((address_space(3)))

typedef __attribute__((ext_vector_type(8))) _Float16 f16x8;
typedef __attribute__((ext_vector_type(4))) float    f32x4;

__device__ __forceinline__ void gload_lds16(const void* g, void* l) {
    __builtin_amdgcn_global_load_lds((const GLOBAL_AS void*)g,
                                     (LDS_AS void*)l, 16, 0, 0);
}

// fp16 quantizer == reference fp_quantize_ste(exp=5, sig=10): RNE + saturate.
__device__ __forceinline__ __half qcvt(float x) {
    x = fminf(fmaxf(x, -65504.f), 65504.f);
    return __float2half(x);   // v_cvt_f16_f32: RNE, subnormals handled
}

// Fused quantization of x and w (both f32 -> f16), one launch, grid-stride.
__global__ void quant_xw_f32_to_f16(const float* __restrict__ xin, int x4,
                                    const float* __restrict__ win, int w4,
                                    __half* __restrict__ xout,
                                    __half* __restrict__ wout) {
    const int stride = gridDim.x * blockDim.x;
    const int tot = x4 + w4;
    for (int i = blockIdx.x * blockDim.x + threadIdx.x; i < tot; i += stride) {
        const bool isx = (i < x4);
        const int  j   = isx ? i : i - x4;
        const float4 f = reinterpret_cast<const float4*>(isx ? xin : win)[j];
        union { __half h[4]; uint2 u; } p;
        p.h[0] = qcvt(f.x);
        p.h[1] = qcvt(f.y);
        p.h[2] = qcvt(f.z);
        p.h[3] = qcvt(f.w);
        reinterpret_cast<uint2*>(isx ? xout : wout)[j] = p.u;
    }
}

// ---------------------------------------------------------------------------
// 256x256 tile, BK=64, 8 waves (2Mx4N), 4 phases/K-tile.
// ROUND 7: (1) read balance 8/4/8/4 — next tile's B0 fragments are read in
// P3 (after vmcnt(6)+barrier confirms their collective arrival), ping-pong
// between the two B register sets; (2) split lgkm waits inside each phase
// (lgkmcnt(4) -> first MFMA half -> lgkmcnt(0) -> second half) so MFMA
// overlaps the phase's own LDS drain; (3) barrier1 kept ONLY at the tile
// boundary (P3, after vmcnt(6)); all WAR chains protected by barrier2s.
//
// Per-phase: P0=(A0,B0) reads af(8); P1=(A0,B1) reads B1(4); P2=(A1,B1)
// reads af(8); P3=(A1,B0) reads next-B0(4).
// Staging: P0: B0(t+1)->nxt  P1: A0(t+2)->cur  P2: B1(t+2)->cur
//          P3: A1(t+2)->cur, then vmcnt(6) == tile t+1 fully arrived.
// lgkm ledgers (in-order DS retirement): P0 wait4 (12 out: 4 prev-B0 + 8 af,
// retires B0 + af[0..1]); P1 wait2 (4 out); P2 wait4 (8 out); P3 none.
// ---------------------------------------------------------------------------
__global__ __launch_bounds__(512, 2) void gemm_f16_8phase(
    const __half* __restrict__ A, const __half* __restrict__ B,
    const float* __restrict__ bias, float* __restrict__ C,
    int M, int N, int K)
{
    __shared__ __align__(16) __half lds[2][2][2][8192];   // 128 KiB
    // layout: [buf](64KiB) [op A=0/B=1](32KiB) [half](16KiB) data

    const int tid  = threadIdx.x;
    const int lane = tid & 63;
    const int wid  = tid >> 6;     // 8 waves
    const int wr   = wid >> 2;     // 0..1 (M)
    const int wc   = wid & 3;      // 0..3 (N)
    const int fr   = lane & 15;
    const int fq   = lane >> 4;

    // bijective XCD swizzle (m204)
    const int nwg = gridDim.x;
    const int qq = nwg >> 3, rr = nwg & 7;
    const int xcd = blockIdx.x & 7, idx = blockIdx.x >> 3;
    const int wgid = (xcd < rr ? xcd * (qq + 1)
                               : rr * (qq + 1) + (xcd - rr) * qq) + idx;
    const int nbn = N >> 8;
    const int tile_m = (wgid / nbn) << 8;
    const int tile_n = (wgid % nbn) << 8;

    // ---- staging source coords (inverse of LDS swizzle, per thread) ----
    const int wbyte = (lane * 16) ^ (((lane >> 5) & 1) << 5);
    const int srow  = ((wid >> 1) << 4) + (wbyte >> 6);   // 0..63
    const int scb   = ((wid & 1) << 6) + (wbyte & 63);    // col byte 0..127
    const char* gA0 = (const char*)A + (size_t)(tile_m + srow) * K * 2 + scb;
    const char* gB0 = (const char*)B + (size_t)(tile_n + srow) * K * 2 + scb;
    const size_t rstep = (size_t)64  * K * 2;   // +64 rows
    const size_t hstep = (size_t)128 * K * 2;   // +1 half (128 rows)
    const int ldst = tid * 16;                  // linear LDS dest byte

    // ---- fragment-read LDS byte addresses (st_16x32 swizzled) ----
    const int woff = (fr * 64 + fq * 16) ^ (((fr >> 3) & 1) << 5);
    const uint32_t lds0 = (uint32_t)(size_t)(LDS_AS const char*)&lds[0][0][0][0];
    const uint32_t aBase = lds0 + (uint32_t)(wr * 8192 + woff);
    const uint32_t bBase = lds0 + 32768u + (uint32_t)(wc * 4096 + woff);

    f32x4 acc[2][2][4][2];
#pragma unroll
    for (int qa = 0; qa < 2; ++qa)
#pragma unroll
        for (int qb = 0; qb < 2; ++qb)
#pragma unroll
            for (int m = 0; m < 4; ++m)
#pragma unroll
                for (int n = 0; n < 2; ++n)
                    acc[qa][qb][m][n] = (f32x4){0.f, 0.f, 0.f, 0.f};

    f16x8 af[4][2];    // A fragments of the current half
    f16x8 bfP[2][2];   // B set ping
    f16x8 bfQ[2][2];   // B set pong

#define STAGE_A(bufi, h, kt) do {                                          \
        char* l_ = (char*)(&lds[bufi][0][h][0]) + ldst;                    \
        const char* g_ = gA0 + (size_t)(kt) * 128 + ((h) ? hstep : 0);     \
        gload_lds16(g_, l_);                                               \
        gload_lds16(g_ + rstep, l_ + 8192);                                \
    } while (0)

#define STAGE_B(bufi, h, kt) do {                                          \
        char* l_ = (char*)(&lds[bufi][1][h][0]) + ldst;                    \
        const char* g_ = gB0 + (size_t)(kt) * 128 + ((h) ? hstep : 0);     \
        gload_lds16(g_, l_);                                               \
        gload_lds16(g_ + rstep, l_ + 8192);                                \
    } while (0)

// inline-asm ds_read_b128 (volatile: program order among reads preserved)
#define DSR(dst, addr, OFF)                                                \
    asm volatile("ds_read_b128 %0, %1 offset:" OFF                         \
                 : "=v"(dst) : "v"(addr))

#define LDGA(bufi, qa) do {                                                \
        const uint32_t a_ = aBase + (bufi) * 65536u + (qa) * 16384u;       \
        DSR(af[0][0], a_, "0");    DSR(af[0][1], a_, "1024");              \
        DSR(af[1][0], a_, "2048"); DSR(af[1][1], a_, "3072");              \
        DSR(af[2][0], a_, "4096"); DSR(af[2][1], a_, "5120");              \
        DSR(af[3][0], a_, "6144"); DSR(af[3][1], a_, "7168");              \
    } while (0)

#define LDGB(dst, bufi, hb) do {                                           \
        const uint32_t b_ = bBase + (bufi) * 65536u + (hb) * 16384u;       \
        DSR(dst[0][0], b_, "0");    DSR(dst[0][1], b_, "1024");            \
        DSR(dst[1][0], b_, "2048"); DSR(dst[1][1], b_, "3072");            \
    } while (0)

#define MMA_PAIR(qa, qb, mm, nn, BF)                                       \
    acc[qa][qb][mm][nn] = __builtin_amdgcn_mfma_f32_16x16x32_f16(          \
        af[mm][0], BF[nn][0], acc[qa][qb][mm][nn], 0, 0, 0);               \
    acc[qa][qb][mm][nn] = __builtin_amdgcn_mfma_f32_16x16x32_f16(          \
        af[mm][1], BF[nn][1], acc[qa][qb][mm][nn], 0, 0, 0);

#define MMA_M01(qa, qb, BF)                                                \
    __builtin_amdgcn_s_setprio(1);                                         \
    MMA_PAIR(qa, qb, 0, 0, BF) MMA_PAIR(qa, qb, 0, 1, BF)                  \
    MMA_PAIR(qa, qb, 1, 0, BF) MMA_PAIR(qa, qb, 1, 1, BF)                  \
    __builtin_amdgcn_s_setprio(0);

#define MMA_M23(qa, qb, BF)                                                \
    __builtin_amdgcn_s_setprio(1);                                         \
    MMA_PAIR(qa, qb, 2, 0, BF) MMA_PAIR(qa, qb, 2, 1, BF)                  \
    MMA_PAIR(qa, qb, 3, 0, BF) MMA_PAIR(qa, qb, 3, 1, BF)                  \
    __builtin_amdgcn_s_setprio(0);

#define MMA_N0(qa, qb, BF)                                                 \
    __builtin_amdgcn_s_setprio(1);                                         \
    MMA_PAIR(qa, qb, 0, 0, BF) MMA_PAIR(qa, qb, 1, 0, BF)                  \
    MMA_PAIR(qa, qb, 2, 0, BF) MMA_PAIR(qa, qb, 3, 0, BF)                  \
    __builtin_amdgcn_s_setprio(0);

#define MMA_N1(qa, qb, BF)                                                 \
    __builtin_amdgcn_s_setprio(1);                                         \
    MMA_PAIR(qa, qb, 0, 1, BF) MMA_PAIR(qa, qb, 1, 1, BF)                  \
    MMA_PAIR(qa, qb, 2, 1, BF) MMA_PAIR(qa, qb, 3, 1, BF)                  \
    __builtin_amdgcn_s_setprio(0);

#define MMA_FULL(qa, qb, BF)                                               \
    MMA_M01(qa, qb, BF) MMA_M23(qa, qb, BF)

// counted lgkm wait + scheduler fence (rule #18)
#define WAITL(NLIT)                                                        \
    asm volatile("s_waitcnt lgkmcnt(" NLIT ")");                           \
    __builtin_amdgcn_sched_barrier(0)

#define BARS()                                                             \
    __builtin_amdgcn_s_barrier();                                          \
    __builtin_amdgcn_sched_barrier(0)

#define TILE_FULL(cur, nxt, kt, B0S, B1S)                                  \
    /* P0: MFMA(A0,B0) | read af<-A0(t) | stage B0(t+1)->nxt */            \
    LDGA(cur, 0); STAGE_B(nxt, 0, (kt) + 1);                               \
    WAITL("4"); MMA_M01(0, 0, B0S);                                        \
    WAITL("0"); MMA_M23(0, 0, B0S);                                        \
    BARS();                                                                \
    /* P1: MFMA(A0,B1) | read B1(t) | stage A0(t+2)->cur */                \
    LDGB(B1S, cur, 1); STAGE_A(cur, 0, (kt) + 2);                          \
    WAITL("2"); MMA_N0(0, 1, B1S);                                         \
    WAITL("0"); MMA_N1(0, 1, B1S);                                         \
    BARS();                                                                \
    /* P2: MFMA(A1,B1) | read af<-A1(t) | stage B1(t+2)->cur */            \
    LDGA(cur, 1); STAGE_B(cur, 1, (kt) + 2);                               \
    WAITL("4"); MMA_M01(1, 1, B1S);                                        \
    WAITL("0"); MMA_M23(1, 1, B1S);                                        \
    BARS();                                                                \
    /* P3: MFMA(A1,B0) | stage A1(t+2)->cur | confirm t+1 | read B0(t+1) */\
    STAGE_A(cur, 1, (kt) + 2);                                             \
    asm volatile("s_waitcnt vmcnt(6)");                                    \
    BARS();                                                                \
    LDGB(B1S, nxt, 0);                                                     \
    __builtin_amdgcn_sched_barrier(0);                                     \
    MMA_FULL(1, 0, B0S);                                                   \
    BARS();

    // ---- prologue: stage tile0 fully + tile1 (A0,B1,A1); B0(1) in-loop ----
    STAGE_A(0, 0, 0); STAGE_B(0, 0, 0); STAGE_B(0, 1, 0); STAGE_A(0, 1, 0);
    STAGE_A(1, 0, 1); STAGE_B(1, 1, 1); STAGE_A(1, 1, 1);
    asm volatile("s_waitcnt vmcnt(6)");   // tile0 arrived (own ledger)
    BARS();                               // collective arrival
    LDGB(bfP, 0, 0);                      // tile0 B0 -> bfP (4 outstanding)

    const int nt = K >> 6;              // even, >= 4 (guarded by launcher)
    for (int kt = 0; kt + 3 < nt; kt += 2) {
        TILE_FULL(0, 1, kt,     bfP, bfQ);
        TILE_FULL(1, 0, kt + 1, bfQ, bfP);
    }

    // ---- tile nt-2 (buf0, B0S=bfP): stage only B0(nt-1); drain at P3 ----
    LDGA(0, 0); STAGE_B(1, 0, nt - 1);
    WAITL("4"); MMA_M01(0, 0, bfP);
    WAITL("0"); MMA_M23(0, 0, bfP);
    BARS();
    LDGB(bfQ, 0, 1);
    WAITL("2"); MMA_N0(0, 1, bfQ);
    WAITL("0"); MMA_N1(0, 1, bfQ);
    BARS();
    LDGA(0, 1);
    WAITL("4"); MMA_M01(1, 1, bfQ);
    WAITL("0"); MMA_M23(1, 1, bfQ);
    BARS();
    asm volatile("s_waitcnt vmcnt(0)");
    BARS();
    LDGB(bfQ, 1, 0);                      // B0(nt-1) -> bfQ
    __builtin_amdgcn_sched_barrier(0);
    MMA_FULL(1, 0, bfP);
    BARS();

    // ---- tile nt-1 (buf1, B0S=bfQ): pure compute ----
    LDGA(1, 0);
    WAITL("4"); MMA_M01(0, 0, bfQ);
    WAITL("0"); MMA_M23(0, 0, bfQ);
    BARS();
    LDGB(bfP, 1, 1);
    WAITL("2"); MMA_N0(0, 1, bfP);
    WAITL("0"); MMA_N1(0, 1, bfP);
    BARS();
    LDGA(1, 1);
    WAITL("4"); MMA_M01(1, 1, bfP);
    WAITL("0"); MMA_M23(1, 1, bfP);
    BARS();
    MMA_FULL(1, 0, bfQ);

    // ---- epilogue: C/D layout col=lane&15, row=fq*4+reg (m89-verified) ----
    float bv[2][2];
#pragma unroll
    for (int qb = 0; qb < 2; ++qb)
#pragma unroll
        for (int n = 0; n < 2; ++n)
            bv[qb][n] = __half2float(qcvt(
                bias[tile_n + qb * 128 + wc * 32 + n * 16 + fr]));

#pragma unroll
    for (int qa = 0; qa < 2; ++qa)
#pragma unroll
        for (int qb = 0; qb < 2; ++qb)
#pragma unroll
            for (int m = 0; m < 4; ++m)
#pragma unroll
                for (int n = 0; n < 2; ++n) {
                    const int col = tile_n + qb * 128 + wc * 32 + n * 16 + fr;
                    const int rowb = tile_m + qa * 128 + wr * 64 + m * 16 + fq * 4;
#pragma unroll
                    for (int r = 0; r < 4; ++r)
                        C[(size_t)(rowb + r) * N + col] =
                            acc[qa][qb][m][n][r] + bv[qb][n];
                }

#undef STAGE_A
#undef STAGE_B
#undef DSR
#undef LDGA
#undef LDGB
#undef MMA_PAIR
#undef MMA_M01
#undef MMA_M23
#undef MMA_N0
#undef MMA_N1
#undef MMA_FULL
#undef WAITL
#undef BARS
#undef TILE_FULL
}

// ---------------------------------------------------------------------------
// Insurance fallback (shape or ws mismatch): fused naive, slow but correct.
// ---------------------------------------------------------------------------
__global__ void qat_gemm_naive(const float* __restrict__ A,
                               const float* __restrict__ B,
                               const float* __restrict__ bias,
                               float* __restrict__ C, int M, int N, int K) {
    const int col = blockIdx.x * blockDim.x + threadIdx.x;
    const int row = blockIdx.y;
    if (col >= N || row >= M) return;
    float s = 0.f;
    for (int k = 0; k < K; ++k) {
        float a = __half2float(qcvt(A[(size_t)row * K + k]));
        float b = __half2float(qcvt(B[(size_t)col * K + k]));
        s += a * b;
    }
    C[(size_t)row * N + col] = s + __half2float(qcvt(bias[col]));
}

// ---------------------------------------------------------------------------
extern "C" void kernel_launch(void* const* d_in, const int* in_sizes, int n_in,
                              void* d_out, int out_size, void* d_ws,
                              size_t ws_size, hipStream_t stream) {
    const float* x = (const float*)d_in[0];
    const float* w = (const float*)d_in[1];
    const float* b = (const float*)d_in[2];
    float* out = (float*)d_out;

    const int xn = in_sizes[0];     // M*K
    const int wn = in_sizes[1];     // N*K
    const int N  = in_sizes[2];     // 4096
    const int K  = wn / N;          // 4096
    const int M  = xn / K;          // 8192

    const size_t need = (size_t)(xn + wn) * sizeof(__half);
    const bool ok = (M % 256 == 0) && (N % 256 == 0) &&
                    (K % 128 == 0) && (K >= 256);

    if (ws_size >= need && ok) {
        __half* xq = (__half*)d_ws;
        __half* wq = xq + xn;

        const int x4 = xn / 4, w4 = wn / 4;
        int blk = ((x4 + w4) + 255) / 256; if (blk > 2048) blk = 2048;
        quant_xw_f32_to_f16<<<blk, 256, 0, stream>>>(x, x4, w, w4, xq, wq);

        dim3 grid((M / 256) * (N / 256));
        gemm_f16_8phase<<<grid, 512, 0, stream>>>(xq, wq, b, out, M, N, K);
    } else {
        dim3 grid((N + 255) / 256, M);
        qat_gemm_naive<<<grid, 256, 0, stream>>>(x, w, b, out, M, N, K);
    }
}